// Round 8
// baseline (86.134 us; speedup 1.0000x reference)
//
#include <hip/hip_runtime.h>
#include <stdint.h>

typedef __attribute__((ext_vector_type(8))) short short8;   // bf16x8 MFMA frag
typedef __attribute__((ext_vector_type(4))) float f32x4;    // fp32x4
typedef unsigned short u16;

#define GROUPS 16
#define MROWS  16384
#define NCH    128
#define TILES  4          // 64-row tiles per block; block covers 256 rows
// grid.x = MROWS/(64*TILES) = 64; grid = (64,16) = 1024 blocks = 4/CU resident

__device__ __forceinline__ u16 f2bf(float f) {
    // fp32 -> bf16 round-to-nearest-even (finite inputs only)
    uint32_t u = __float_as_uint(f);
    u += 0x7FFFu + ((u >> 16) & 1u);
    return (u16)(u >> 16);
}

// ---------------------------------------------------------------------------
// Phase 1: Q = H_0*...*H_127, emitted frag-linear bf16: 16B chunk (c*16+s)
// holds Qt[c][8s..8s+7] = Q[8s..8s+7][c].  Unchanged (passing since R1).
// ---------------------------------------------------------------------------
__global__ __launch_bounds__(256) void build_q(const float* __restrict__ w,
                                               u16* __restrict__ qt) {
    __shared__ float wt[128 * 128];
    const int g   = blockIdx.y;
    const int rb  = blockIdx.x;
    const int tid = threadIdx.x;
    const float* wg = w + (size_t)g * NCH * NCH;

    const int ci = tid & 127;
    float den = 0.f;
    for (int r = 0; r < 128; r += 4) {
        float a0 = wg[(r + 0) * 128 + ci];
        float a1 = wg[(r + 1) * 128 + ci];
        float a2 = wg[(r + 2) * 128 + ci];
        float a3 = wg[(r + 3) * 128 + ci];
        den += a0 * a0 + a1 * a1 + a2 * a2 + a3 * a3;
    }
    if (tid < 128) wt[tid] = sqrtf(2.0f / den);
    __syncthreads();
    const float scl = wt[ci];
    __syncthreads();

    {
        const int h = tid >> 7;
        for (int p = 0; p < 64; ++p) {
            int r = 2 * p + h;
            wt[ci * 128 + ((r + 4 * ci) & 127)] = wg[r * 128 + ci] * scl;
        }
    }
    __syncthreads();

    const int t = rb * 16 + (tid >> 4);
    const int s = tid & 15;
    float q[8];
#pragma unroll
    for (int u = 0; u < 2; ++u)
#pragma unroll
        for (int e = 0; e < 4; ++e)
            q[u * 4 + e] = (4 * s + 64 * u + e == t) ? 1.0f : 0.0f;

    const f32x4* wt4 = (const f32x4*)wt;
    for (int i = 0; i < 128; ++i) {
        f32x4 v0 = wt4[i * 32 + ((s + 0  + i) & 31)];
        f32x4 v1 = wt4[i * 32 + ((s + 16 + i) & 31)];
        float pa = q[0] * v0.x + q[1] * v0.y + q[2] * v0.z + q[3] * v0.w;
        float pb = q[4] * v1.x + q[5] * v1.y + q[6] * v1.z + q[7] * v1.w;
        pa += pb;
        pa += __shfl_xor(pa, 1);
        pa += __shfl_xor(pa, 2);
        pa += __shfl_xor(pa, 4);
        pa += __shfl_xor(pa, 8);
        q[0] -= pa * v0.x; q[1] -= pa * v0.y; q[2] -= pa * v0.z; q[3] -= pa * v0.w;
        q[4] -= pa * v1.x; q[5] -= pa * v1.y; q[6] -= pa * v1.z; q[7] -= pa * v1.w;
    }

    u16* qg = qt + (size_t)g * NCH * NCH;
#pragma unroll
    for (int u = 0; u < 2; ++u)
#pragma unroll
        for (int e = 0; e < 4; ++e) {
            int c = 4 * s + 64 * u + e;
            qg[(c * 16 + (t >> 3)) * 8 + (t & 7)] = f2bf(q[u * 4 + e]);
        }
}

// ---------------------------------------------------------------------------
// Phase 2: out[g] = x[g] * Q[g].  Residency-first design:
//  - N split across waves: wave wv -> cols wv*32..+31; its Q frags live in
//    32 VGPRs (2 nt x 4 kb x short8), preloaded once from frag-linear qt.
//  - LDS = ONE 32KB x-tile (64 rows fp32), staged by global_load_lds with
//    pre-swizzled source (^((row&7)<<4)); b128 frag reads conflict-free.
//  - launch_bounds(256,4) -> VGPR<=128 -> 4 blocks/CU resident = 16 waves/CU;
//    stage/compute overlap across blocks (TLP), simple 2-barrier rhythm.
// ---------------------------------------------------------------------------
__global__ __launch_bounds__(256, 4) void apply_q(const float* __restrict__ x,
                                                  const u16* __restrict__ qt,
                                                  float* __restrict__ out) {
    __shared__ __align__(16) char xs[32768];   // 64 rows x 512 B, swizzled
    const int g   = blockIdx.y;
    const int bx  = blockIdx.x;          // 0..63
    const int tid = threadIdx.x;
    const int wv  = tid >> 6;
    const int l   = tid & 63;
    const int lr  = l & 15;
    const int lb  = l >> 4;

    // ---- Q frags in registers: lane (lr,lb) holds, for nt in {0,1}, kb 0..3:
    //      Q^T[c = wv*32+nt*16+lr][k = kb*32+lb*8 .. +7]  = chunk c*16 + kb*4+lb
    const short8* qg = (const short8*)(qt + (size_t)g * NCH * NCH);
    short8 qf0[4], qf1[4];
#pragma unroll
    for (int kb = 0; kb < 4; ++kb) {
        qf0[kb] = qg[(wv * 32 +      lr) * 16 + kb * 4 + lb];
        qf1[kb] = qg[(wv * 32 + 16 + lr) * 16 + kb * 4 + lb];
    }

    const size_t rowbase = (size_t)g * MROWS + (size_t)bx * (64 * TILES);
    const char* xg = (const char*)(x + rowbase * NCH);

    for (int t = 0; t < TILES; ++t) {
        if (t) __syncthreads();                    // xs free for overwrite

        // stage 64 rows: linear LDS dest, swizzled global source (m173)
#pragma unroll
        for (int p = 0; p < 8; ++p) {
            int f   = p * 256 + tid;               // 0..2047
            int row = f >> 5;                      // 0..63
            int off = ((f & 31) * 16) ^ ((row & 7) << 4);
            __builtin_amdgcn_global_load_lds(
                (const __attribute__((address_space(1))) void*)
                    (xg + (size_t)t * 32768 + row * 512 + off),
                (__attribute__((address_space(3))) void*)(xs + f * 16),
                16, 0, 0);
        }
        __syncthreads();                           // drains vmcnt; tile ready

#pragma unroll
        for (int rg = 0; rg < 4; ++rg) {
            const int row = rg * 16 + lr;
            short8 afr[4];
#pragma unroll
            for (int kb = 0; kb < 4; ++kb) {
                int b0 = row * 512 + ((kb * 128 + lb * 32)      ^ ((row & 7) << 4));
                int b1 = row * 512 + ((kb * 128 + lb * 32 + 16) ^ ((row & 7) << 4));
                f32x4 v0 = *(const f32x4*)(xs + b0);
                f32x4 v1 = *(const f32x4*)(xs + b1);
                short8 a;
                a[0] = (short)f2bf(v0.x); a[1] = (short)f2bf(v0.y);
                a[2] = (short)f2bf(v0.z); a[3] = (short)f2bf(v0.w);
                a[4] = (short)f2bf(v1.x); a[5] = (short)f2bf(v1.y);
                a[6] = (short)f2bf(v1.z); a[7] = (short)f2bf(v1.w);
                afr[kb] = a;
            }

            f32x4 acc0 = {0.f, 0.f, 0.f, 0.f};
            f32x4 acc1 = {0.f, 0.f, 0.f, 0.f};
#pragma unroll
            for (int kb = 0; kb < 4; ++kb) {
                acc0 = __builtin_amdgcn_mfma_f32_16x16x32_bf16(qf0[kb], afr[kb], acc0, 0, 0, 0);
                acc1 = __builtin_amdgcn_mfma_f32_16x16x32_bf16(qf1[kb], afr[kb], acc1, 0, 0, 0);
            }

            // D[c][m]: m_local = lane&15 = lr (row), c_local = lb*4+reg
            float* orow = out + (rowbase + (size_t)t * 64 + row) * NCH + wv * 32;
            *(f32x4*)(orow +      lb * 4) = acc0;
            *(f32x4*)(orow + 16 + lb * 4) = acc1;
        }
    }
}

extern "C" void kernel_launch(void* const* d_in, const int* in_sizes, int n_in,
                              void* d_out, int out_size, void* d_ws, size_t ws_size,
                              hipStream_t stream) {
    const float* x = (const float*)d_in[0];
    const float* w = (const float*)d_in[1];
    float* out = (float*)d_out;
    u16* qtw = (u16*)d_ws;               // Qt bf16 frag-linear: 512 KiB

    build_q<<<dim3(8, GROUPS), 256, 0, stream>>>(w, qtw);
    apply_q<<<dim3(MROWS / (64 * TILES), GROUPS), 256, 0, stream>>>(x, qtw, out);
}